// Round 7
// baseline (355.745 us; speedup 1.0000x reference)
//
#include <hip/hip_runtime.h>
#include <cstdint>
#include <cstddef>

// GCN 2-layer, commuted form:  Agg(z) @ W == Agg(z @ W)  (Agg mixes rows, W mixes cols)
//   s1 = bf16(dinv ⊙ x)
//   h' = dinv ⊙ relu( [dinv ⊙ (s1_i + Σ_nbr s1_r)] @ W1 + b1 )   (bf16, pre-scaled for L2)
//   out =               [dinv ⊙ (h'_i + Σ_nbr h'_r)] @ W2 + b2    (fp32)
//
// R7: barrier-free register-gather fused kernel.
//  - Wave independently owns 16 nodes. Lane (lm,quad) gathers node lm's
//    columns {quad*8 + s*32 | s=0..3} as 4 fp32[8] register accumulators —
//    EXACTLY the MFMA A-fragment layout (lane holds A[m=lm][k=quad*8+j]).
//    4-neighbor unroll x 4 chunks = 16 outstanding 16B gathers per lane.
//  - No LDS round-trip for A, no gather->MFMA barrier, no inter-wave sync.
//  - B-fragments from global Wt (32KB, L2-resident; A has no LDS dep now).
//  - Epilogue stages D through a PRIVATE per-wave LDS slice (u16[16][136] =
//    4.25KB; fp32 overlay [16][68] in 2 passes for L2) -> coalesced stores.
//  - LDS 17.4KB, launch_bounds(256,4) -> 16 waves/CU (R5: 52.7KB, 12 waves,
//    2 barriers; R5 counters: Occ 22%, all pipes <31% = latency-bound).

typedef unsigned int u32;
typedef unsigned short u16;
typedef __attribute__((ext_vector_type(8))) short short8;   // 8 bf16 (4 VGPRs)
typedef __attribute__((ext_vector_type(4))) float f32x4;    // MFMA acc / native vec

__device__ __forceinline__ float bf2f(u32 lo16) {
  union { u32 u; float f; } c; c.u = lo16 << 16; return c.f;
}
__device__ __forceinline__ u32 f2bf(float f) {  // round-to-nearest-even
  union { float f; u32 u; } c; c.f = f;
  return (c.u + 0x7fffu + ((c.u >> 16) & 1u)) >> 16;
}
__device__ __forceinline__ void acc8(float* a, uint4 v) {
  a[0] += bf2f(v.x & 0xffff); a[1] += bf2f(v.x >> 16);
  a[2] += bf2f(v.y & 0xffff); a[3] += bf2f(v.y >> 16);
  a[4] += bf2f(v.z & 0xffff); a[5] += bf2f(v.z >> 16);
  a[6] += bf2f(v.w & 0xffff); a[7] += bf2f(v.w >> 16);
}

// zero cnt; W1,W2 [k][n] f32 -> Wt [n][k] bf16; zero row N of s1 and hp.
__global__ __launch_bounds__(256) void zero_wt_kernel(
    const float* __restrict__ W1, const float* __restrict__ W2,
    u16* __restrict__ Wt1, u16* __restrict__ Wt2,
    u16* __restrict__ s1, u16* __restrict__ hp,
    int* __restrict__ cnt, int N) {
  int gt = blockIdx.x * 256 + threadIdx.x;
  if (gt < N) cnt[gt] = 0;
  if (gt < 32768) {
    const float* W = (gt < 16384) ? W1 : W2;
    u16* Wt = (gt < 16384) ? Wt1 : Wt2;
    int idx = gt & 16383;
    Wt[(idx & 127) * 128 + (idx >> 7)] = (u16)f2bf(W[idx]);
  }
  if (gt < 16) {
    ((uint4*)(s1 + (size_t)N * 128))[gt] = make_uint4(0, 0, 0, 0);
    ((uint4*)(hp + (size_t)N * 128))[gt] = make_uint4(0, 0, 0, 0);
  }
}

__global__ __launch_bounds__(256) void count_kernel(
    const int* __restrict__ cols, const int* __restrict__ rows,
    int* __restrict__ cnt, int E, int N) {
  int e = blockIdx.x * 256 + threadIdx.x;
  if (e >= E) return;
  int c = cols[e];
  int r = rows[e];
  if ((unsigned)c >= (unsigned)N || (unsigned)r >= (unsigned)N) return;
  atomicAdd(&cnt[c], 1);
}

// exclusive scan of cnt[N] -> rowptr[N] (chunk-local); emits dinv (fused)
__global__ __launch_bounds__(256) void scan1_kernel(
    const int* __restrict__ cnt, int* __restrict__ rowptr,
    int* __restrict__ bsum, float* __restrict__ dinv, int N) {
  __shared__ int sd[256];
  int t = threadIdx.x;
  int base = blockIdx.x * 1024 + t * 4;
  int c0 = (base + 0 < N) ? cnt[base + 0] : 0;
  int c1 = (base + 1 < N) ? cnt[base + 1] : 0;
  int c2 = (base + 2 < N) ? cnt[base + 2] : 0;
  int c3 = (base + 3 < N) ? cnt[base + 3] : 0;
  if (base + 0 < N) dinv[base + 0] = rsqrtf((float)c0 + 1.0f);
  if (base + 1 < N) dinv[base + 1] = rsqrtf((float)c1 + 1.0f);
  if (base + 2 < N) dinv[base + 2] = rsqrtf((float)c2 + 1.0f);
  if (base + 3 < N) dinv[base + 3] = rsqrtf((float)c3 + 1.0f);
  int s = c0 + c1 + c2 + c3;
  sd[t] = s;
  __syncthreads();
  for (int off = 1; off < 256; off <<= 1) {
    int v = (t >= off) ? sd[t - off] : 0;
    __syncthreads();
    sd[t] += v;
    __syncthreads();
  }
  int excl = sd[t] - s;
  if (base + 0 < N) rowptr[base + 0] = excl;
  if (base + 1 < N) rowptr[base + 1] = excl + c0;
  if (base + 2 < N) rowptr[base + 2] = excl + c0 + c1;
  if (base + 3 < N) rowptr[base + 3] = excl + c0 + c1 + c2;
  if (t == 255) bsum[blockIdx.x] = sd[255];
}

__global__ __launch_bounds__(128) void scan2_kernel(
    const int* __restrict__ bsum, int* __restrict__ bsum2,
    int* __restrict__ rowptr, int NB, int N) {
  __shared__ int sd[128];
  int t = threadIdx.x;
  int v = (t < NB) ? bsum[t] : 0;
  sd[t] = v;
  __syncthreads();
  for (int off = 1; off < 128; off <<= 1) {
    int u = (t >= off) ? sd[t - off] : 0;
    __syncthreads();
    sd[t] += u;
    __syncthreads();
  }
  bsum2[t] = sd[t] - v;
  if (t == NB - 1) rowptr[N] = sd[t];
}

// rowptr += chunk offset (scan3)  AND  s1 = bf16(dinv ⊙ x)  (fused)
__global__ __launch_bounds__(256) void finalize_kernel(
    const float* __restrict__ x, const float* __restrict__ dinv,
    int* __restrict__ rowptr, const int* __restrict__ bsum2,
    u16* __restrict__ s1, int N, int NB) {
  int b = blockIdx.x, t = threadIdx.x;
  if (b < NB) {
    int base = b * 1024 + t * 4;
    int add = bsum2[b];
#pragma unroll
    for (int k = 0; k < 4; k++)
      if (base + k < N) rowptr[base + k] += add;
  }
  int total = N * 16;  // 16B chunks per node row
  for (int idx = b * 256 + t; idx < total; idx += gridDim.x * 256) {
    int node = idx >> 4, l = idx & 15;
    float di = dinv[node];
    const float* xp = x + (size_t)node * 128 + l * 8;
    float4 v0 = *(const float4*)xp;
    float4 v1 = *(const float4*)(xp + 4);
    uint4 p;
    p.x = f2bf(di * v0.x) | (f2bf(di * v0.y) << 16);
    p.y = f2bf(di * v0.z) | (f2bf(di * v0.w) << 16);
    p.z = f2bf(di * v1.x) | (f2bf(di * v1.y) << 16);
    p.w = f2bf(di * v1.z) | (f2bf(di * v1.w) << 16);
    ((uint4*)s1)[idx] = p;
  }
}

// cnt doubles as the cursor: atomicSub returns old count, pos = old-1 in [0,deg)
__global__ __launch_bounds__(256) void fill_kernel(
    const int* __restrict__ cols, const int* __restrict__ rows,
    const int* __restrict__ rowptr, int* __restrict__ cnt,
    int* __restrict__ adj, int E, int N) {
  int e = blockIdx.x * 256 + threadIdx.x;
  if (e >= E) return;
  int c = cols[e];
  int r = rows[e];
  if ((unsigned)c >= (unsigned)N || (unsigned)r >= (unsigned)N) return;
  int pos = atomicSub(&cnt[c], 1) - 1;
  if (pos >= 0) adj[rowptr[c] + pos] = r;
}

// ---------------------------------------------------------------------------
// Fused register-gather + GEMM. Block = 256 thr (4 INDEPENDENT waves), 64
// nodes/block (16/wave). No __syncthreads anywhere.
// Gather: lane (lm,quad) owns node wrow0+lm, columns {s*32+quad*8..+7}:
//   a[s][8] fp32 accumulates self + Σ neighbors (zero-row N pads dummies).
//   Unroll-4 neighbors x 4 chunk-streams = 16 outstanding 16B loads/lane.
// MFMA: afrag[s] = bf16(di * a[s]) is directly the A-fragment
//   (A: lane holds A[m=lane&15][k=quad*8+j], m89/m118-verified).
//   B from global Wt [n][k] (L2-resident 32KB): B[k=quad*8+j][n=lane&15].
//   D: col=lane&15, row=quad*4+reg.
// Epilogue: per-wave private LDS slice (no barrier):
//   L1: u16[16][136] staging -> hp = bf16(dinv_row*relu(acc+b1)), uint4 stores.
//   L2: fp32 overlay [16][68], 2 half-row passes -> nontemporal f32x4 stores.
// ---------------------------------------------------------------------------
template <int LAYER>
__global__ __launch_bounds__(256, 4) void fused_ag_kernel(
    const u16* __restrict__ src, const int* __restrict__ rowptr,
    const int* __restrict__ adj, const float* __restrict__ dinv,
    const float* __restrict__ bias, const u16* __restrict__ Wt,
    void* __restrict__ out, int N) {
  __shared__ __align__(16) u16 Cs[4][16][136];   // 17408 B, per-wave slices
  const int tid = threadIdx.x;
  const int wave = tid >> 6, lane = tid & 63;
  const int lm = lane & 15, quad = lane >> 4;
  const int wrow0 = blockIdx.x * 64 + wave * 16;  // wave's 16 nodes
  const int node = wrow0 + lm;

  // ---- register gather
  float a[4][8];
#pragma unroll
  for (int s = 0; s < 4; s++)
#pragma unroll
    for (int e = 0; e < 8; e++) a[s][e] = 0.f;
  float di = 0.f;
  if (node < N) {
    di = dinv[node];
    const uint4* srow = (const uint4*)src + (size_t)node * 16 + quad;
    uint4 sv[4];
#pragma unroll
    for (int s = 0; s < 4; s++) sv[s] = srow[s * 4];
#pragma unroll
    for (int s = 0; s < 4; s++) acc8(a[s], sv[s]);

    int beg = rowptr[node], end = rowptr[node + 1];
    for (int j = beg; j < end; j += 4) {
      int sidx[4];
#pragma unroll
      for (int k = 0; k < 4; k++) {
        int jj = j + k;
        sidx[k] = (jj < end) ? adj[jj] : N;  // N = zero row (exact 0.0 adds)
      }
      uint4 v[4][4];
#pragma unroll
      for (int k = 0; k < 4; k++) {
        const uint4* p = (const uint4*)src + (size_t)sidx[k] * 16 + quad;
#pragma unroll
        for (int s = 0; s < 4; s++) v[k][s] = p[s * 4];
      }
#pragma unroll
      for (int k = 0; k < 4; k++)
#pragma unroll
        for (int s = 0; s < 4; s++) acc8(a[s], v[k][s]);
    }
  }

  // ---- convert to A-fragments in-register (dinv-scaled)
  short8 afrag[4];
#pragma unroll
  for (int s = 0; s < 4; s++)
#pragma unroll
    for (int e = 0; e < 8; e++) afrag[s][e] = (short)f2bf(di * a[s][e]);

  // ---- MFMA: B-fragments from global Wt (L2-resident)
  const u16* wbase = Wt + lm * 128 + quad * 8;  // + nt*2048 + s*32
  f32x4 macc[8];
#pragma unroll
  for (int nt = 0; nt < 8; nt++) macc[nt] = (f32x4){0.f, 0.f, 0.f, 0.f};
#pragma unroll
  for (int s = 0; s < 4; s++) {
    short8 bf[8];
#pragma unroll
    for (int nt = 0; nt < 8; nt++)
      bf[nt] = *(const short8*)(wbase + nt * 2048 + s * 32);
#pragma unroll
    for (int nt = 0; nt < 8; nt++)
      macc[nt] = __builtin_amdgcn_mfma_f32_16x16x32_bf16(afrag[s], bf[nt], macc[nt], 0, 0, 0);
  }

  float bv[8];
#pragma unroll
  for (int nt = 0; nt < 8; nt++) bv[nt] = bias[nt * 16 + lm];

  // ---- epilogue through per-wave LDS slice (same-wave write->read, no barrier)
  if (LAYER == 1) {
    u16 (*cs)[136] = Cs[wave];
#pragma unroll
    for (int r = 0; r < 4; r++) {
      float dv = __shfl(di, quad * 4 + r);  // dinv of OUTPUT row (held by lane quad*4+r)
#pragma unroll
      for (int nt = 0; nt < 8; nt++) {
        float v = fmaxf(macc[nt][r] + bv[nt], 0.f);
        cs[quad * 4 + r][nt * 16 + lm] = (u16)f2bf(v * dv);
      }
    }
    u16* C = (u16*)out;
#pragma unroll
    for (int i = 0; i < 4; i++) {
      int linear = lane + i * 64;   // 0..255 = 16 rows x 16 uint4-chunks
      int row = linear >> 4, c8 = linear & 15;
      int grow = wrow0 + row;
      if (grow < N)
        *(uint4*)(C + (size_t)grow * 128 + c8 * 8) = *(const uint4*)&cs[row][c8 * 8];
    }
  } else {
    float (*fs)[68] = (float(*)[68])Cs[wave];  // 16*68*4 = 4352 B overlay
    float* C = (float*)out;
#pragma unroll
    for (int p = 0; p < 2; p++) {
#pragma unroll
      for (int r = 0; r < 4; r++)
#pragma unroll
        for (int t = 0; t < 4; t++)
          fs[quad * 4 + r][t * 16 + lm] = macc[p * 4 + t][r] + bv[p * 4 + t];
#pragma unroll
      for (int i = 0; i < 4; i++) {
        int linear = lane + i * 64;  // 16 rows x 16 f32x4-chunks (64 cols)
        int row = linear >> 4, c4 = linear & 15;
        int grow = wrow0 + row;
        if (grow < N) {
          f32x4 v = *(const f32x4*)&fs[row][c4 * 4];
          __builtin_nontemporal_store(v, (f32x4*)(C + (size_t)grow * 128 + p * 64 + c4 * 4));
        }
      }
    }
  }
}

extern "C" void kernel_launch(void* const* d_in, const int* in_sizes, int n_in,
                              void* d_out, int out_size, void* d_ws, size_t ws_size,
                              hipStream_t stream) {
  const float* x  = (const float*)d_in[0];
  const int*   ei = (const int*)d_in[1];
  const float* W1 = (const float*)d_in[2];
  const float* b1 = (const float*)d_in[3];
  const float* W2 = (const float*)d_in[4];
  const float* b2 = (const float*)d_in[5];
  float* out = (float*)d_out;

  const int F = 128;
  const int N = in_sizes[0] / F;
  const int E = in_sizes[1] / 2;
  const int* rows = ei;       // edge_index[0] = source
  const int* cols = ei + E;   // edge_index[1] = destination

  // workspace layout (~55 MB)
  u16*   Wt1    = (u16*)d_ws;                          // 128*128 bf16 (W1^T)
  u16*   Wt2    = Wt1 + 128 * 128;                     // 128*128 bf16 (W2^T)
  u16*   s1     = Wt2 + 128 * 128;                     // (N+1)*128 bf16 (dinv⊙x + zero row)
  u16*   hp     = s1 + (size_t)(N + 1) * F;            // (N+1)*128 bf16 (dinv⊙h + zero row)
  float* dinv   = (float*)(hp + (size_t)(N + 1) * F);  // N f32
  int*   cnt    = (int*)(dinv + N);                    // N i32 (count, then cursor)
  int*   rowptr = cnt + N;                             // N+1 i32
  int*   adj    = rowptr + (N + 1);                    // E i32
  int*   bsum   = adj + E;                             // 128 i32
  int*   bsum2  = bsum + 128;                          // 128 i32

  const int NB = (N + 1023) / 1024;
  int eblocks = (E + 255) / 256;
  int nblocks = (N + 255) / 256;
  int fblocks = (NB > 784) ? NB : 784;

  zero_wt_kernel<<<nblocks, 256, 0, stream>>>(W1, W2, Wt1, Wt2, s1, hp, cnt, N);
  count_kernel<<<eblocks, 256, 0, stream>>>(cols, rows, cnt, E, N);
  scan1_kernel<<<NB, 256, 0, stream>>>(cnt, rowptr, bsum, dinv, N);
  scan2_kernel<<<1, 128, 0, stream>>>(bsum, bsum2, rowptr, NB, N);
  finalize_kernel<<<fblocks, 256, 0, stream>>>(x, dinv, rowptr, bsum2, s1, N, NB);
  fill_kernel<<<eblocks, 256, 0, stream>>>(cols, rows, rowptr, cnt, adj, E, N);

  int gblocks = (N + 63) / 64;
  // layer 1: hp = dinv ⊙ relu([dinv ⊙ Agg-sum(s1)] @ W1 + b1)  (bf16)
  fused_ag_kernel<1><<<gblocks, 256, 0, stream>>>(
      s1, rowptr, adj, dinv, b1, Wt1, hp, N);
  // layer 2: out = [dinv ⊙ Agg-sum(hp)] @ W2 + b2  (fp32)
  fused_ag_kernel<2><<<gblocks, 256, 0, stream>>>(
      hp, rowptr, adj, dinv, b2, Wt2, out, N);
}

// Round 8
// 247.989 us; speedup vs baseline: 1.4345x; 1.4345x over previous
//
#include <hip/hip_runtime.h>
#include <cstdint>
#include <cstddef>

// GCN 2-layer, commuted form:  Agg(z) @ W == Agg(z @ W)  (Agg mixes rows, W mixes cols)
//   s1 = bf16(dinv ⊙ x)
//   h' = dinv ⊙ relu( [dinv ⊙ (s1_i + Σ_nbr s1_r)] @ W1 + b1 )   (bf16, pre-scaled for L2)
//   out =               [dinv ⊙ (h'_i + Σ_nbr h'_r)] @ W2 + b2    (fp32)
//
// R8 = R5 (best fused: 45us/layer, Occ 22%, 12 waves/CU) with 512-thr blocks:
//   same 64-node tile, same LDS (52.5KB -> 3 blocks/CU), but 8 waves/block
//   -> 24 waves/CU (75% cap). Gather code byte-identical to R5 (R7's register
//   gather spilled: VGPR cap 64 vs ~160 needed -> scratch = 111MB WRITE_SIZE).
//   MFMA: wave pair per 16-row m-tile (wave = (mt, n-half)), acc[4] = 16 VGPR.
//   W stays in LDS (R6 showed B-from-global on MFMA path costs more than it
//   saves). launch_bounds(512,6) -> VGPR cap 85 (R5 gather measured 68).

typedef unsigned int u32;
typedef unsigned short u16;
typedef __attribute__((ext_vector_type(8))) short short8;   // 8 bf16 (4 VGPRs)
typedef __attribute__((ext_vector_type(4))) float f32x4;    // MFMA acc / native vec

__device__ __forceinline__ float bf2f(u32 lo16) {
  union { u32 u; float f; } c; c.u = lo16 << 16; return c.f;
}
__device__ __forceinline__ u32 f2bf(float f) {  // round-to-nearest-even
  union { float f; u32 u; } c; c.f = f;
  return (c.u + 0x7fffu + ((c.u >> 16) & 1u)) >> 16;
}

// zero cnt; W1,W2 [k][n] f32 -> Wt [n][k] bf16; zero row N of s1 and hp.
__global__ __launch_bounds__(256) void zero_wt_kernel(
    const float* __restrict__ W1, const float* __restrict__ W2,
    u16* __restrict__ Wt1, u16* __restrict__ Wt2,
    u16* __restrict__ s1, u16* __restrict__ hp,
    int* __restrict__ cnt, int N) {
  int gt = blockIdx.x * 256 + threadIdx.x;
  if (gt < N) cnt[gt] = 0;
  if (gt < 32768) {
    const float* W = (gt < 16384) ? W1 : W2;
    u16* Wt = (gt < 16384) ? Wt1 : Wt2;
    int idx = gt & 16383;
    Wt[(idx & 127) * 128 + (idx >> 7)] = (u16)f2bf(W[idx]);
  }
  if (gt < 16) {
    ((uint4*)(s1 + (size_t)N * 128))[gt] = make_uint4(0, 0, 0, 0);
    ((uint4*)(hp + (size_t)N * 128))[gt] = make_uint4(0, 0, 0, 0);
  }
}

__global__ __launch_bounds__(256) void count_kernel(
    const int* __restrict__ cols, const int* __restrict__ rows,
    int* __restrict__ cnt, int E, int N) {
  int e = blockIdx.x * 256 + threadIdx.x;
  if (e >= E) return;
  int c = cols[e];
  int r = rows[e];
  if ((unsigned)c >= (unsigned)N || (unsigned)r >= (unsigned)N) return;
  atomicAdd(&cnt[c], 1);
}

// exclusive scan of cnt[N] -> rowptr[N] (chunk-local); emits dinv (fused)
__global__ __launch_bounds__(256) void scan1_kernel(
    const int* __restrict__ cnt, int* __restrict__ rowptr,
    int* __restrict__ bsum, float* __restrict__ dinv, int N) {
  __shared__ int sd[256];
  int t = threadIdx.x;
  int base = blockIdx.x * 1024 + t * 4;
  int c0 = (base + 0 < N) ? cnt[base + 0] : 0;
  int c1 = (base + 1 < N) ? cnt[base + 1] : 0;
  int c2 = (base + 2 < N) ? cnt[base + 2] : 0;
  int c3 = (base + 3 < N) ? cnt[base + 3] : 0;
  if (base + 0 < N) dinv[base + 0] = rsqrtf((float)c0 + 1.0f);
  if (base + 1 < N) dinv[base + 1] = rsqrtf((float)c1 + 1.0f);
  if (base + 2 < N) dinv[base + 2] = rsqrtf((float)c2 + 1.0f);
  if (base + 3 < N) dinv[base + 3] = rsqrtf((float)c3 + 1.0f);
  int s = c0 + c1 + c2 + c3;
  sd[t] = s;
  __syncthreads();
  for (int off = 1; off < 256; off <<= 1) {
    int v = (t >= off) ? sd[t - off] : 0;
    __syncthreads();
    sd[t] += v;
    __syncthreads();
  }
  int excl = sd[t] - s;
  if (base + 0 < N) rowptr[base + 0] = excl;
  if (base + 1 < N) rowptr[base + 1] = excl + c0;
  if (base + 2 < N) rowptr[base + 2] = excl + c0 + c1;
  if (base + 3 < N) rowptr[base + 3] = excl + c0 + c1 + c2;
  if (t == 255) bsum[blockIdx.x] = sd[255];
}

__global__ __launch_bounds__(128) void scan2_kernel(
    const int* __restrict__ bsum, int* __restrict__ bsum2,
    int* __restrict__ rowptr, int NB, int N) {
  __shared__ int sd[128];
  int t = threadIdx.x;
  int v = (t < NB) ? bsum[t] : 0;
  sd[t] = v;
  __syncthreads();
  for (int off = 1; off < 128; off <<= 1) {
    int u = (t >= off) ? sd[t - off] : 0;
    __syncthreads();
    sd[t] += u;
    __syncthreads();
  }
  bsum2[t] = sd[t] - v;
  if (t == NB - 1) rowptr[N] = sd[t];
}

// rowptr += chunk offset (scan3)  AND  s1 = bf16(dinv ⊙ x)  (fused)
__global__ __launch_bounds__(256) void finalize_kernel(
    const float* __restrict__ x, const float* __restrict__ dinv,
    int* __restrict__ rowptr, const int* __restrict__ bsum2,
    u16* __restrict__ s1, int N, int NB) {
  int b = blockIdx.x, t = threadIdx.x;
  if (b < NB) {
    int base = b * 1024 + t * 4;
    int add = bsum2[b];
#pragma unroll
    for (int k = 0; k < 4; k++)
      if (base + k < N) rowptr[base + k] += add;
  }
  int total = N * 16;  // 16B chunks per node row
  for (int idx = b * 256 + t; idx < total; idx += gridDim.x * 256) {
    int node = idx >> 4, l = idx & 15;
    float di = dinv[node];
    const float* xp = x + (size_t)node * 128 + l * 8;
    float4 v0 = *(const float4*)xp;
    float4 v1 = *(const float4*)(xp + 4);
    uint4 p;
    p.x = f2bf(di * v0.x) | (f2bf(di * v0.y) << 16);
    p.y = f2bf(di * v0.z) | (f2bf(di * v0.w) << 16);
    p.z = f2bf(di * v1.x) | (f2bf(di * v1.y) << 16);
    p.w = f2bf(di * v1.z) | (f2bf(di * v1.w) << 16);
    ((uint4*)s1)[idx] = p;
  }
}

// cnt doubles as the cursor: atomicSub returns old count, pos = old-1 in [0,deg)
__global__ __launch_bounds__(256) void fill_kernel(
    const int* __restrict__ cols, const int* __restrict__ rows,
    const int* __restrict__ rowptr, int* __restrict__ cnt,
    int* __restrict__ adj, int E, int N) {
  int e = blockIdx.x * 256 + threadIdx.x;
  if (e >= E) return;
  int c = cols[e];
  int r = rows[e];
  if ((unsigned)c >= (unsigned)N || (unsigned)r >= (unsigned)N) return;
  int pos = atomicSub(&cnt[c], 1) - 1;
  if (pos >= 0) adj[rowptr[c] + pos] = r;
}

// ---------------------------------------------------------------------------
// Fused aggregate + GEMM. Block = 512 thr (8 waves), 64 nodes.
// LDS 52.5 KiB -> 3 blocks/CU -> 24 waves/CU.
// Phase 1 (gather): quarter-wave per node, 2 passes x 32 nodes; fp32
//   accumulate of src[self] + Σ src[nbr] (zero-row N pads dummies); write
//   dinv*g to Gs (bf16). Identical inner loop to R5 (measured VGPR 68).
// Phase 2 (MFMA): wave = (mt = wave>>1, nhalf = wave&1): 16 rows x 64 cols,
//   4 nt x 4 k-steps of 16x16x32 bf16, A from Gs, B from Ws.
//   Layouts (m89/m118-verified):
//   A: lane holds A[m=lane&15][k=quad*8+j];  B: B[k=quad*8+j][n=lane&15]
//   C/D: col=lane&15, row=quad*4+reg
// Epilogue L1: hp = bf16(dinv*relu(acc+b1)) via Gs reuse, coalesced uint4.
// Epilogue L2: out = fp32(acc+b2) via fp32 overlay [64][132] of Ws region,
//   nontemporal f32x4 stores.
// ---------------------------------------------------------------------------
template <int LAYER>
__global__ __launch_bounds__(512, 6) void fused_ag_kernel(
    const uint4* __restrict__ src, const int* __restrict__ rowptr,
    const int* __restrict__ adj, const float* __restrict__ dinv,
    const float* __restrict__ bias, const uint4* __restrict__ Wt,
    void* __restrict__ out, int N) {
  __shared__ __align__(16) u16 smem[128 * 136 + 64 * 136];  // Ws | Gs
  __shared__ float dv_s[64];
  u16 (*Ws)[136] = (u16(*)[136])smem;                 // 34816 B (W, [n][k])
  u16 (*Gs)[136] = (u16(*)[136])(smem + 128 * 136);   // 17408 B (gathered rows)
  const int tid = threadIdx.x;
  const int row0 = blockIdx.x * 64;

  // stage W tile (2048 x 16B, 512 thr x 4)
#pragma unroll
  for (int i = 0; i < 4; i++) {
    int linear = tid + i * 512;
    int n = linear >> 4, kq = linear & 15;
    *(uint4*)&Ws[n][kq * 8] = Wt[linear];
  }

  // ---- gather phase: 2 passes x 32 nodes (quarter-wave per node)
  const int qw = tid >> 4;   // 0..31
  const int l = tid & 15;
#pragma unroll
  for (int pass = 0; pass < 2; ++pass) {
    int lrow = pass * 32 + qw;
    int node = row0 + lrow;
    float a[8] = {0.f, 0.f, 0.f, 0.f, 0.f, 0.f, 0.f, 0.f};
    float di = 0.f;
    if (node < N) {
      di = dinv[node];
      uint4 sv = src[(size_t)node * 16 + l];
      a[0] = bf2f(sv.x & 0xffff); a[1] = bf2f(sv.x >> 16);
      a[2] = bf2f(sv.y & 0xffff); a[3] = bf2f(sv.y >> 16);
      a[4] = bf2f(sv.z & 0xffff); a[5] = bf2f(sv.z >> 16);
      a[6] = bf2f(sv.w & 0xffff); a[7] = bf2f(sv.w >> 16);
      int beg = rowptr[node], end = rowptr[node + 1];
      for (int j = beg; j < end; j += 8) {
        int sidx[8];
#pragma unroll
        for (int k = 0; k < 8; k++) {
          int jj = j + k;
          sidx[k] = (jj < end) ? adj[jj] : N;  // N = zero row
        }
        uint4 v[8];
#pragma unroll
        for (int k = 0; k < 8; k++) v[k] = src[(size_t)sidx[k] * 16 + l];
#pragma unroll
        for (int k = 0; k < 8; k++) {
          a[0] += bf2f(v[k].x & 0xffff); a[1] += bf2f(v[k].x >> 16);
          a[2] += bf2f(v[k].y & 0xffff); a[3] += bf2f(v[k].y >> 16);
          a[4] += bf2f(v[k].z & 0xffff); a[5] += bf2f(v[k].z >> 16);
          a[6] += bf2f(v[k].w & 0xffff); a[7] += bf2f(v[k].w >> 16);
        }
      }
    }
    uint4 p;
    p.x = f2bf(di * a[0]) | (f2bf(di * a[1]) << 16);
    p.y = f2bf(di * a[2]) | (f2bf(di * a[3]) << 16);
    p.z = f2bf(di * a[4]) | (f2bf(di * a[5]) << 16);
    p.w = f2bf(di * a[6]) | (f2bf(di * a[7]) << 16);
    *(uint4*)&Gs[lrow][l * 8] = p;
    if (l == 0) dv_s[lrow] = di;
  }
  __syncthreads();

  // ---- MFMA phase: wave (mt, nhalf) owns rows mt*16..+15, cols nhalf*64..+63
  const int wave = tid >> 6, lane = tid & 63;
  const int lm = lane & 15, quad = lane >> 4;
  const int m0 = (wave >> 1) * 16;
  const int nh = wave & 1;
  f32x4 acc[4];
#pragma unroll
  for (int nt = 0; nt < 4; nt++) acc[nt] = (f32x4){0.f, 0.f, 0.f, 0.f};
#pragma unroll
  for (int k0 = 0; k0 < 128; k0 += 32) {
    short8 afrag = *(const short8*)&Gs[m0 + lm][k0 + quad * 8];
#pragma unroll
    for (int nt = 0; nt < 4; nt++) {
      short8 bfrag = *(const short8*)&Ws[(nh * 4 + nt) * 16 + lm][k0 + quad * 8];
      acc[nt] = __builtin_amdgcn_mfma_f32_16x16x32_bf16(afrag, bfrag, acc[nt], 0, 0, 0);
    }
  }

  float bv[4];
#pragma unroll
  for (int nt = 0; nt < 4; nt++) bv[nt] = bias[(nh * 4 + nt) * 16 + lm];

  __syncthreads();  // Ws/Gs dead; reuse as epilogue staging
  if (LAYER == 1) {
    int rbase = m0 + quad * 4;
#pragma unroll
    for (int r = 0; r < 4; r++) {
      int lrow = rbase + r;
      float dv = dv_s[lrow];
#pragma unroll
      for (int nt = 0; nt < 4; nt++) {
        float v = fmaxf(acc[nt][r] + bv[nt], 0.f);
        Gs[lrow][(nh * 4 + nt) * 16 + lm] = (u16)f2bf(v * dv);
      }
    }
    __syncthreads();
    u16* C = (u16*)out;
#pragma unroll
    for (int i = 0; i < 2; i++) {
      int linear = tid + i * 512;  // 0..1023 = 64 rows x 16 uint4-chunks
      int row = linear >> 4, c8 = linear & 15;
      int grow = row0 + row;
      if (grow < N)
        *(uint4*)(C + (size_t)grow * 128 + c8 * 8) = *(const uint4*)&Gs[row][c8 * 8];
    }
  } else {
    float (*Fs)[132] = (float(*)[132])smem;  // 64*132*4 = 33792 B (Ws region)
    int rbase = m0 + quad * 4;
#pragma unroll
    for (int r = 0; r < 4; r++) {
      int lrow = rbase + r;
#pragma unroll
      for (int nt = 0; nt < 4; nt++)
        Fs[lrow][(nh * 4 + nt) * 16 + lm] = acc[nt][r] + bv[nt];
    }
    __syncthreads();
    float* C = (float*)out;
#pragma unroll
    for (int i = 0; i < 4; i++) {
      int linear = tid + i * 512;  // 0..2047 = 64 rows x 32 f32x4-chunks
      int row = linear >> 5, c4 = linear & 31;
      int grow = row0 + row;
      if (grow < N) {
        f32x4 v = *(const f32x4*)&Fs[row][c4 * 4];
        __builtin_nontemporal_store(v, (f32x4*)(C + (size_t)grow * 128 + c4 * 4));
      }
    }
  }
}

extern "C" void kernel_launch(void* const* d_in, const int* in_sizes, int n_in,
                              void* d_out, int out_size, void* d_ws, size_t ws_size,
                              hipStream_t stream) {
  const float* x  = (const float*)d_in[0];
  const int*   ei = (const int*)d_in[1];
  const float* W1 = (const float*)d_in[2];
  const float* b1 = (const float*)d_in[3];
  const float* W2 = (const float*)d_in[4];
  const float* b2 = (const float*)d_in[5];
  float* out = (float*)d_out;

  const int F = 128;
  const int N = in_sizes[0] / F;
  const int E = in_sizes[1] / 2;
  const int* rows = ei;       // edge_index[0] = source
  const int* cols = ei + E;   // edge_index[1] = destination

  // workspace layout (~55 MB)
  u16*   Wt1    = (u16*)d_ws;                          // 128*128 bf16 (W1^T)
  u16*   Wt2    = Wt1 + 128 * 128;                     // 128*128 bf16 (W2^T)
  u16*   s1     = Wt2 + 128 * 128;                     // (N+1)*128 bf16 (dinv⊙x + zero row)
  u16*   hp     = s1 + (size_t)(N + 1) * F;            // (N+1)*128 bf16 (dinv⊙h + zero row)
  float* dinv   = (float*)(hp + (size_t)(N + 1) * F);  // N f32
  int*   cnt    = (int*)(dinv + N);                    // N i32 (count, then cursor)
  int*   rowptr = cnt + N;                             // N+1 i32
  int*   adj    = rowptr + (N + 1);                    // E i32
  int*   bsum   = adj + E;                             // 128 i32
  int*   bsum2  = bsum + 128;                          // 128 i32

  const int NB = (N + 1023) / 1024;
  int eblocks = (E + 255) / 256;
  int nblocks = (N + 255) / 256;
  int fblocks = (NB > 784) ? NB : 784;

  zero_wt_kernel<<<nblocks, 256, 0, stream>>>(W1, W2, Wt1, Wt2, s1, hp, cnt, N);
  count_kernel<<<eblocks, 256, 0, stream>>>(cols, rows, cnt, E, N);
  scan1_kernel<<<NB, 256, 0, stream>>>(cnt, rowptr, bsum, dinv, N);
  scan2_kernel<<<1, 128, 0, stream>>>(bsum, bsum2, rowptr, NB, N);
  finalize_kernel<<<fblocks, 256, 0, stream>>>(x, dinv, rowptr, bsum2, s1, N, NB);
  fill_kernel<<<eblocks, 256, 0, stream>>>(cols, rows, rowptr, cnt, adj, E, N);

  int gblocks = (N + 63) / 64;
  // layer 1: hp = dinv ⊙ relu([dinv ⊙ Agg-sum(s1)] @ W1 + b1)  (bf16)
  fused_ag_kernel<1><<<gblocks, 512, 0, stream>>>(
      (const uint4*)s1, rowptr, adj, dinv, b1, (const uint4*)Wt1, hp, N);
  // layer 2: out = [dinv ⊙ Agg-sum(hp)] @ W2 + b2  (fp32)
  fused_ag_kernel<2><<<gblocks, 512, 0, stream>>>(
      (const uint4*)hp, rowptr, adj, dinv, b2, (const uint4*)Wt2, out, N);
}

// Round 9
// 246.375 us; speedup vs baseline: 1.4439x; 1.0066x over previous
//
#include <hip/hip_runtime.h>
#include <cstdint>
#include <cstddef>

// GCN 2-layer, commuted form:  Agg(z) @ W == Agg(z @ W)  (Agg mixes rows, W mixes cols)
//   s1 = bf16(dinv ⊙ x)
//   h' = dinv ⊙ relu( [dinv ⊙ (s1_i + Σ_nbr s1_r)] @ W1 + b1 )   (bf16, pre-scaled for L2)
//   out =               [dinv ⊙ (h'_i + Σ_nbr h'_r)] @ W2 + b2    (fp32)
//
// R9 = R8 (248us; fused 512thr/64-node/52.5KB-LDS/24-waves-CU) + setup
// consolidation:
//  - scan2 folded into finalize (each block re-scans bsum[256] in LDS; the
//    1-block scan2 kernel was a whole-GPU serialization point).
//  - cnt zeroing via hipMemsetAsync (graph-capturable); zero_wt -> 128 blocks.
//  - fused gather: rowptr for BOTH passes hoisted to top (one fewer dependent
//    latency hop); bias loads hoisted above MFMA k-loop.
// Occupancy analysis says 24 waves/CU is the practical cap for this structure
// (Ws-in-LDS required per R6; reg-gather needs >64 VGPR per R7) — this round
// attacks launch-chain overhead instead.

typedef unsigned int u32;
typedef unsigned short u16;
typedef __attribute__((ext_vector_type(8))) short short8;   // 8 bf16 (4 VGPRs)
typedef __attribute__((ext_vector_type(4))) float f32x4;    // MFMA acc / native vec

__device__ __forceinline__ float bf2f(u32 lo16) {
  union { u32 u; float f; } c; c.u = lo16 << 16; return c.f;
}
__device__ __forceinline__ u32 f2bf(float f) {  // round-to-nearest-even
  union { float f; u32 u; } c; c.f = f;
  return (c.u + 0x7fffu + ((c.u >> 16) & 1u)) >> 16;
}

// W1,W2 [k][n] f32 -> Wt [n][k] bf16; zero row N of s1 and hp. 128 blocks.
__global__ __launch_bounds__(256) void wt_kernel(
    const float* __restrict__ W1, const float* __restrict__ W2,
    u16* __restrict__ Wt1, u16* __restrict__ Wt2,
    u16* __restrict__ s1, u16* __restrict__ hp, int N) {
  int gt = blockIdx.x * 256 + threadIdx.x;  // 0..32767
  const float* W = (gt < 16384) ? W1 : W2;
  u16* Wt = (gt < 16384) ? Wt1 : Wt2;
  int idx = gt & 16383;
  Wt[(idx & 127) * 128 + (idx >> 7)] = (u16)f2bf(W[idx]);
  if (gt < 16) {
    ((uint4*)(s1 + (size_t)N * 128))[gt] = make_uint4(0, 0, 0, 0);
    ((uint4*)(hp + (size_t)N * 128))[gt] = make_uint4(0, 0, 0, 0);
  }
}

__global__ __launch_bounds__(256) void count_kernel(
    const int* __restrict__ cols, const int* __restrict__ rows,
    int* __restrict__ cnt, int E, int N) {
  int e = blockIdx.x * 256 + threadIdx.x;
  if (e >= E) return;
  int c = cols[e];
  int r = rows[e];
  if ((unsigned)c >= (unsigned)N || (unsigned)r >= (unsigned)N) return;
  atomicAdd(&cnt[c], 1);
}

// exclusive scan of cnt[N] -> rowptr[N] (chunk-local); emits dinv (fused)
__global__ __launch_bounds__(256) void scan1_kernel(
    const int* __restrict__ cnt, int* __restrict__ rowptr,
    int* __restrict__ bsum, float* __restrict__ dinv, int N) {
  __shared__ int sd[256];
  int t = threadIdx.x;
  int base = blockIdx.x * 1024 + t * 4;
  int c0 = (base + 0 < N) ? cnt[base + 0] : 0;
  int c1 = (base + 1 < N) ? cnt[base + 1] : 0;
  int c2 = (base + 2 < N) ? cnt[base + 2] : 0;
  int c3 = (base + 3 < N) ? cnt[base + 3] : 0;
  if (base + 0 < N) dinv[base + 0] = rsqrtf((float)c0 + 1.0f);
  if (base + 1 < N) dinv[base + 1] = rsqrtf((float)c1 + 1.0f);
  if (base + 2 < N) dinv[base + 2] = rsqrtf((float)c2 + 1.0f);
  if (base + 3 < N) dinv[base + 3] = rsqrtf((float)c3 + 1.0f);
  int s = c0 + c1 + c2 + c3;
  sd[t] = s;
  __syncthreads();
  for (int off = 1; off < 256; off <<= 1) {
    int v = (t >= off) ? sd[t - off] : 0;
    __syncthreads();
    sd[t] += v;
    __syncthreads();
  }
  int excl = sd[t] - s;
  if (base + 0 < N) rowptr[base + 0] = excl;
  if (base + 1 < N) rowptr[base + 1] = excl + c0;
  if (base + 2 < N) rowptr[base + 2] = excl + c0 + c1;
  if (base + 3 < N) rowptr[base + 3] = excl + c0 + c1 + c2;
  if (t == 255) bsum[blockIdx.x] = sd[255];
}

// rowptr += chunk offset (bsum re-scan, folds old scan2+scan3)
// AND s1 = bf16(dinv ⊙ x). NB <= 256 (N <= 262144).
__global__ __launch_bounds__(256) void finalize_kernel(
    const float* __restrict__ x, const float* __restrict__ dinv,
    int* __restrict__ rowptr, const int* __restrict__ bsum,
    u16* __restrict__ s1, int N, int NB) {
  int b = blockIdx.x, t = threadIdx.x;
  if (b < NB) {  // uniform branch per block -> barriers legal
    __shared__ int sd[256];
    int v = (t < NB) ? bsum[t] : 0;
    sd[t] = v;
    __syncthreads();
    for (int off = 1; off < 256; off <<= 1) {
      int u = (t >= off) ? sd[t - off] : 0;
      __syncthreads();
      sd[t] += u;
      __syncthreads();
    }
    int add = (b == 0) ? 0 : sd[b - 1];  // exclusive chunk prefix
    int base = b * 1024 + t * 4;
#pragma unroll
    for (int k = 0; k < 4; k++)
      if (base + k < N) rowptr[base + k] += add;
    if (b == 0 && t == 255) rowptr[N] = sd[255];  // total edges kept
  }
  int total = N * 16;  // 16B chunks per node row
  for (int idx = b * 256 + t; idx < total; idx += gridDim.x * 256) {
    int node = idx >> 4, l = idx & 15;
    float di = dinv[node];
    const float* xp = x + (size_t)node * 128 + l * 8;
    float4 v0 = *(const float4*)xp;
    float4 v1 = *(const float4*)(xp + 4);
    uint4 p;
    p.x = f2bf(di * v0.x) | (f2bf(di * v0.y) << 16);
    p.y = f2bf(di * v0.z) | (f2bf(di * v0.w) << 16);
    p.z = f2bf(di * v1.x) | (f2bf(di * v1.y) << 16);
    p.w = f2bf(di * v1.z) | (f2bf(di * v1.w) << 16);
    ((uint4*)s1)[idx] = p;
  }
}

// cnt doubles as the cursor: atomicSub returns old count, pos = old-1 in [0,deg)
__global__ __launch_bounds__(256) void fill_kernel(
    const int* __restrict__ cols, const int* __restrict__ rows,
    const int* __restrict__ rowptr, int* __restrict__ cnt,
    int* __restrict__ adj, int E, int N) {
  int e = blockIdx.x * 256 + threadIdx.x;
  if (e >= E) return;
  int c = cols[e];
  int r = rows[e];
  if ((unsigned)c >= (unsigned)N || (unsigned)r >= (unsigned)N) return;
  int pos = atomicSub(&cnt[c], 1) - 1;
  if (pos >= 0) adj[rowptr[c] + pos] = r;
}

// ---------------------------------------------------------------------------
// Fused aggregate + GEMM. Block = 512 thr (8 waves), 64 nodes.
// LDS 52.5 KiB -> 3 blocks/CU -> 24 waves/CU.
// Phase 1 (gather): quarter-wave per node, 2 passes x 32 nodes; rowptr for
//   both passes hoisted; fp32 accumulate of src[self] + Σ src[nbr] (zero-row
//   N pads dummies); write dinv*g to Gs (bf16).
// Phase 2 (MFMA): wave = (mt = wave>>1, nhalf = wave&1): 16 rows x 64 cols,
//   4 nt x 4 k-steps of 16x16x32 bf16, A from Gs, B from Ws.
//   Layouts (m89/m118-verified):
//   A: lane holds A[m=lane&15][k=quad*8+j];  B: B[k=quad*8+j][n=lane&15]
//   C/D: col=lane&15, row=quad*4+reg
// Epilogue L1: hp = bf16(dinv*relu(acc+b1)) via Gs reuse, coalesced uint4.
// Epilogue L2: out = fp32(acc+b2) via fp32 overlay [64][132] of Ws region,
//   nontemporal f32x4 stores.
// ---------------------------------------------------------------------------
template <int LAYER>
__global__ __launch_bounds__(512, 6) void fused_ag_kernel(
    const uint4* __restrict__ src, const int* __restrict__ rowptr,
    const int* __restrict__ adj, const float* __restrict__ dinv,
    const float* __restrict__ bias, const uint4* __restrict__ Wt,
    void* __restrict__ out, int N) {
  __shared__ __align__(16) u16 smem[128 * 136 + 64 * 136];  // Ws | Gs
  __shared__ float dv_s[64];
  u16 (*Ws)[136] = (u16(*)[136])smem;                 // 34816 B (W, [n][k])
  u16 (*Gs)[136] = (u16(*)[136])(smem + 128 * 136);   // 17408 B (gathered rows)
  const int tid = threadIdx.x;
  const int row0 = blockIdx.x * 64;

  // stage W tile (2048 x 16B, 512 thr x 4)
#pragma unroll
  for (int i = 0; i < 4; i++) {
    int linear = tid + i * 512;
    int n = linear >> 4, kq = linear & 15;
    *(uint4*)&Ws[n][kq * 8] = Wt[linear];
  }

  // ---- gather phase: 2 passes x 32 nodes (quarter-wave per node)
  const int qw = tid >> 4;   // 0..31
  const int l = tid & 15;
  // hoist rowptr for both passes (removes a dependent hop inside each pass)
  int begs[2], ends[2];
#pragma unroll
  for (int p = 0; p < 2; ++p) {
    int node = row0 + p * 32 + qw;
    begs[p] = 0; ends[p] = 0;
    if (node < N) { begs[p] = rowptr[node]; ends[p] = rowptr[node + 1]; }
  }
#pragma unroll
  for (int pass = 0; pass < 2; ++pass) {
    int lrow = pass * 32 + qw;
    int node = row0 + lrow;
    float a[8] = {0.f, 0.f, 0.f, 0.f, 0.f, 0.f, 0.f, 0.f};
    float di = 0.f;
    if (node < N) {
      di = dinv[node];
      uint4 sv = src[(size_t)node * 16 + l];
      a[0] = bf2f(sv.x & 0xffff); a[1] = bf2f(sv.x >> 16);
      a[2] = bf2f(sv.y & 0xffff); a[3] = bf2f(sv.y >> 16);
      a[4] = bf2f(sv.z & 0xffff); a[5] = bf2f(sv.z >> 16);
      a[6] = bf2f(sv.w & 0xffff); a[7] = bf2f(sv.w >> 16);
      int beg = begs[pass], end = ends[pass];
      for (int j = beg; j < end; j += 8) {
        int sidx[8];
#pragma unroll
        for (int k = 0; k < 8; k++) {
          int jj = j + k;
          sidx[k] = (jj < end) ? adj[jj] : N;  // N = zero row
        }
        uint4 v[8];
#pragma unroll
        for (int k = 0; k < 8; k++) v[k] = src[(size_t)sidx[k] * 16 + l];
#pragma unroll
        for (int k = 0; k < 8; k++) {
          a[0] += bf2f(v[k].x & 0xffff); a[1] += bf2f(v[k].x >> 16);
          a[2] += bf2f(v[k].y & 0xffff); a[3] += bf2f(v[k].y >> 16);
          a[4] += bf2f(v[k].z & 0xffff); a[5] += bf2f(v[k].z >> 16);
          a[6] += bf2f(v[k].w & 0xffff); a[7] += bf2f(v[k].w >> 16);
        }
      }
    }
    uint4 p;
    p.x = f2bf(di * a[0]) | (f2bf(di * a[1]) << 16);
    p.y = f2bf(di * a[2]) | (f2bf(di * a[3]) << 16);
    p.z = f2bf(di * a[4]) | (f2bf(di * a[5]) << 16);
    p.w = f2bf(di * a[6]) | (f2bf(di * a[7]) << 16);
    *(uint4*)&Gs[lrow][l * 8] = p;
    if (l == 0) dv_s[lrow] = di;
  }
  __syncthreads();

  // ---- MFMA phase: wave (mt, nhalf) owns rows mt*16..+15, cols nhalf*64..+63
  const int wave = tid >> 6, lane = tid & 63;
  const int lm = lane & 15, quad = lane >> 4;
  const int m0 = (wave >> 1) * 16;
  const int nh = wave & 1;

  float bv[4];  // hoisted above k-loop: latency hides under MFMA
#pragma unroll
  for (int nt = 0; nt < 4; nt++) bv[nt] = bias[(nh * 4 + nt) * 16 + lm];

  f32x4 acc[4];
#pragma unroll
  for (int nt = 0; nt < 4; nt++) acc[nt] = (f32x4){0.f, 0.f, 0.f, 0.f};
#pragma unroll
  for (int k0 = 0; k0 < 128; k0 += 32) {
    short8 afrag = *(const short8*)&Gs[m0 + lm][k0 + quad * 8];
#pragma unroll
    for (int nt = 0; nt < 4; nt++) {
      short8 bfrag = *(const short8*)&Ws[(nh * 4 + nt) * 16 + lm][k0 + quad * 8];
      acc[nt] = __builtin_amdgcn_mfma_f32_16x16x32_bf16(afrag, bfrag, acc[nt], 0, 0, 0);
    }
  }

  __syncthreads();  // Ws/Gs dead; reuse as epilogue staging
  if (LAYER == 1) {
    int rbase = m0 + quad * 4;
#pragma unroll
    for (int r = 0; r < 4; r++) {
      int lrow = rbase + r;
      float dv = dv_s[lrow];
#pragma unroll
      for (int nt = 0; nt < 4; nt++) {
        float v = fmaxf(acc[nt][r] + bv[nt], 0.f);
        Gs[lrow][(nh * 4 + nt) * 16 + lm] = (u16)f2bf(v * dv);
      }
    }
    __syncthreads();
    u16* C = (u16*)out;
#pragma unroll
    for (int i = 0; i < 2; i++) {
      int linear = tid + i * 512;  // 0..1023 = 64 rows x 16 uint4-chunks
      int row = linear >> 4, c8 = linear & 15;
      int grow = row0 + row;
      if (grow < N)
        *(uint4*)(C + (size_t)grow * 128 + c8 * 8) = *(const uint4*)&Gs[row][c8 * 8];
    }
  } else {
    float (*Fs)[132] = (float(*)[132])smem;  // 64*132*4 = 33792 B (Ws region)
    int rbase = m0 + quad * 4;
#pragma unroll
    for (int r = 0; r < 4; r++) {
      int lrow = rbase + r;
#pragma unroll
      for (int nt = 0; nt < 4; nt++)
        Fs[lrow][(nh * 4 + nt) * 16 + lm] = acc[nt][r] + bv[nt];
    }
    __syncthreads();
    float* C = (float*)out;
#pragma unroll
    for (int i = 0; i < 4; i++) {
      int linear = tid + i * 512;  // 0..2047 = 64 rows x 32 f32x4-chunks
      int row = linear >> 5, c4 = linear & 31;
      int grow = row0 + row;
      if (grow < N) {
        f32x4 v = *(const f32x4*)&Fs[row][c4 * 4];
        __builtin_nontemporal_store(v, (f32x4*)(C + (size_t)grow * 128 + c4 * 4));
      }
    }
  }
}

extern "C" void kernel_launch(void* const* d_in, const int* in_sizes, int n_in,
                              void* d_out, int out_size, void* d_ws, size_t ws_size,
                              hipStream_t stream) {
  const float* x  = (const float*)d_in[0];
  const int*   ei = (const int*)d_in[1];
  const float* W1 = (const float*)d_in[2];
  const float* b1 = (const float*)d_in[3];
  const float* W2 = (const float*)d_in[4];
  const float* b2 = (const float*)d_in[5];
  float* out = (float*)d_out;

  const int F = 128;
  const int N = in_sizes[0] / F;
  const int E = in_sizes[1] / 2;
  const int* rows = ei;       // edge_index[0] = source
  const int* cols = ei + E;   // edge_index[1] = destination

  // workspace layout (~55 MB)
  u16*   Wt1    = (u16*)d_ws;                          // 128*128 bf16 (W1^T)
  u16*   Wt2    = Wt1 + 128 * 128;                     // 128*128 bf16 (W2^T)
  u16*   s1     = Wt2 + 128 * 128;                     // (N+1)*128 bf16 (dinv⊙x + zero row)
  u16*   hp     = s1 + (size_t)(N + 1) * F;            // (N+1)*128 bf16 (dinv⊙h + zero row)
  float* dinv   = (float*)(hp + (size_t)(N + 1) * F);  // N f32
  int*   cnt    = (int*)(dinv + N);                    // N i32 (count, then cursor)
  int*   rowptr = cnt + N;                             // N+1 i32
  int*   adj    = rowptr + (N + 1);                    // E i32
  int*   bsum   = adj + E;                             // 256 i32

  const int NB = (N + 1023) / 1024;  // <= 256 (N <= 262144)
  int eblocks = (E + 255) / 256;
  int fblocks = (NB > 784) ? NB : 784;

  hipMemsetAsync(cnt, 0, (size_t)N * sizeof(int), stream);
  wt_kernel<<<128, 256, 0, stream>>>(W1, W2, Wt1, Wt2, s1, hp, N);
  count_kernel<<<eblocks, 256, 0, stream>>>(cols, rows, cnt, E, N);
  scan1_kernel<<<NB, 256, 0, stream>>>(cnt, rowptr, bsum, dinv, N);
  finalize_kernel<<<fblocks, 256, 0, stream>>>(x, dinv, rowptr, bsum, s1, N, NB);
  fill_kernel<<<eblocks, 256, 0, stream>>>(cols, rows, rowptr, cnt, adj, E, N);

  int gblocks = (N + 63) / 64;
  // layer 1: hp = dinv ⊙ relu([dinv ⊙ Agg-sum(s1)] @ W1 + b1)  (bf16)
  fused_ag_kernel<1><<<gblocks, 512, 0, stream>>>(
      (const uint4*)s1, rowptr, adj, dinv, b1, (const uint4*)Wt1, hp, N);
  // layer 2: out = [dinv ⊙ Agg-sum(hp)] @ W2 + b2  (fp32)
  fused_ag_kernel<2><<<gblocks, 512, 0, stream>>>(
      (const uint4*)hp, rowptr, adj, dinv, b2, (const uint4*)Wt2, out, N);
}